// Round 9
// baseline (651.186 us; speedup 1.0000x reference)
//
#include <hip/hip_runtime.h>

#define N_RID  100000
#define N_CELL 400000
#define NCOLS  4
#define NE     100000
#define D      64
#define TOTE   (NCOLS * NE)          // 400000 edges per direction
#define TILE   64                    // rows per block

typedef __attribute__((ext_vector_type(8))) short bf16x8;
typedef __attribute__((ext_vector_type(4))) float f32x4;

__device__ inline unsigned short f2bf(float f) {
    unsigned int u = __float_as_uint(f);
    return (unsigned short)((u + 0x7FFF + ((u >> 16) & 1)) >> 16);
}
// packed 2xf32 -> 2xbf16 (low16 = a, high16 = b)
__device__ inline unsigned int cvtpk(float a, float b) {
    unsigned int r;
    asm("v_cvt_pk_bf16_f32 %0, %1, %2" : "=v"(r) : "v"(a), "v"(b));
    return r;
}
// byte offset within a [16 rows][128B] bf16 tile, XOR-swizzled
__device__ inline int swz(int row, int kbyte) {
    return row * 128 + (kbyte ^ ((row & 7) << 4));
}

// ================================================================ CSR build
__global__ void hist_kernel(const int* __restrict__ dst, int* __restrict__ cnt,
                            int ndst) {
    int t = blockIdx.x * 256 + threadIdx.x;
    if (t >= TOTE) return;
    int c = t / NE;
    atomicAdd(&cnt[c * ndst + dst[t]], 1);
}

__global__ void scan1(const int* __restrict__ in, int* __restrict__ out,
                      int* __restrict__ csum, int n) {
    __shared__ int lds[256];
    int base = blockIdx.x * 1024 + threadIdx.x * 4;
    int v0 = 0, v1 = 0, v2 = 0, v3 = 0;
    if (base + 0 < n) v0 = in[base + 0];
    if (base + 1 < n) v1 = in[base + 1];
    if (base + 2 < n) v2 = in[base + 2];
    if (base + 3 < n) v3 = in[base + 3];
    int tsum = v0 + v1 + v2 + v3;
    lds[threadIdx.x] = tsum;
    __syncthreads();
    for (int off = 1; off < 256; off <<= 1) {
        int x = (threadIdx.x >= off) ? lds[threadIdx.x - off] : 0;
        __syncthreads();
        lds[threadIdx.x] += x;
        __syncthreads();
    }
    int excl = lds[threadIdx.x] - tsum;
    if (base + 0 < n) out[base + 0] = excl;
    if (base + 1 < n) out[base + 1] = excl + v0;
    if (base + 2 < n) out[base + 2] = excl + v0 + v1;
    if (base + 3 < n) out[base + 3] = excl + v0 + v1 + v2;
    if (threadIdx.x == 255) csum[blockIdx.x] = lds[255];
}

__global__ void scan2(int* __restrict__ a, int m) {
    __shared__ int lds[256];
    int per = (m + 255) >> 8;
    int st = threadIdx.x * per;
    int s = 0;
    for (int i = 0; i < per; ++i) if (st + i < m) s += a[st + i];
    lds[threadIdx.x] = s;
    __syncthreads();
    for (int off = 1; off < 256; off <<= 1) {
        int x = (threadIdx.x >= off) ? lds[threadIdx.x - off] : 0;
        __syncthreads();
        lds[threadIdx.x] += x;
        __syncthreads();
    }
    int run = lds[threadIdx.x] - s;
    for (int i = 0; i < per; ++i) if (st + i < m) { int v = a[st + i]; a[st + i] = run; run += v; }
}

__global__ void scan3(int* __restrict__ out, const int* __restrict__ csum, int n) {
    int i = blockIdx.x * 256 + threadIdx.x;
    if (i < n) out[i] += csum[i >> 10];
}

__global__ void set_sentinels(int* __restrict__ pF, int* __restrict__ pR) {
    if (threadIdx.x == 0) {
        pF[NCOLS * N_CELL] = TOTE;
        pR[NCOLS * N_RID]  = TOTE;
    }
}

__global__ void fill_kernel(const int* __restrict__ dst, const int* __restrict__ src,
                            const int* __restrict__ ptr, int* __restrict__ cnt,
                            int* __restrict__ col, int ndst) {
    int t = blockIdx.x * 256 + threadIdx.x;
    if (t >= TOTE) return;
    int c = t / NE;
    int bin = c * ndst + dst[t];
    int old = atomicSub(&cnt[bin], 1);
    col[ptr[bin] + old - 1] = src[t];
}

// ---------------- W prep: Wt[c][j][k] = bf16(W[c][k][j]) for 4 weight sets
__global__ void prep_w(const float* __restrict__ Wa, const float* __restrict__ Wb,
                       const float* __restrict__ Wc, const float* __restrict__ Wd,
                       unsigned short* __restrict__ Ta, unsigned short* __restrict__ Tb,
                       unsigned short* __restrict__ Tc, unsigned short* __restrict__ Td) {
    int t = blockIdx.x * 256 + threadIdx.x;
    if (t >= NCOLS * D * D) return;
    int c = t >> 12, jk = t & 4095, j = jk >> 6, k = jk & 63;
    int s = (c * D + k) * D + j;
    Ta[t] = f2bf(Wa[s]);
    Tb[t] = f2bf(Wb[s]);
    Tc[t] = f2bf(Wc[s]);
    Td[t] = f2bf(Wd[s]);
}

// ============================ unified SAGE layer kernel ======================
// Wave w owns rows [w*16, w*16+16). Gather is straight-line batched: deg<=2
// bins (>=92%) handled with branch-free masked loads (all independent, one
// waitcnt batch per edge slot); rare deg>2 bins take an exec-masked fallback.
__global__ void __launch_bounds__(256, 2) sage_fused(
        const float* __restrict__ h_dst, const float* __restrict__ h_src,
        const int* __restrict__ ptr, const int* __restrict__ col,
        const unsigned short* __restrict__ Wt, const float* __restrict__ bias,
        const float* __restrict__ mu_d, const float* __restrict__ mu_s,
        float* __restrict__ out, float* __restrict__ csum, int n_dst) {
    __shared__ int pl[NCOLS][TILE + 1];              // ~1 KB
    __shared__ unsigned short aHi[4][16 * D];        // 8 KB (2 KB per wave)
    __shared__ unsigned short aLo[4][16 * D];        // 8 KB

    const int tid = threadIdx.x, w = tid >> 6, l = tid & 63;
    const int g = l >> 3, q = l & 7;                 // 8-lane group, lane-in-group
    const int row0 = blockIdx.x * TILE;

    // coalesced ptr prefetch (clamped; sentinel entry valid)
    for (int i = tid; i < NCOLS * (TILE + 1); i += 256) {
        int cc = i / (TILE + 1), r = i % (TILE + 1);
        pl[cc][r] = ptr[(size_t)cc * n_dst + min(row0 + r, n_dst)];
    }

    // self term (h_dst - mu_d) for the wave's 2 owned rows, fanned to 4 relations
    float4 t0[NCOLS][2], t1[NCOLS][2];
#pragma unroll
    for (int i = 0; i < 2; ++i) {
        int re = min(row0 + w * 16 + i * 8 + g, n_dst - 1);
        const float4* hp = (const float4*)(h_dst + (size_t)re * D);
        float4 v0 = hp[2 * q], v1 = hp[2 * q + 1];
        if (mu_d) {
            float4 m0 = ((const float4*)mu_d)[2 * q], m1 = ((const float4*)mu_d)[2 * q + 1];
            v0.x -= m0.x; v0.y -= m0.y; v0.z -= m0.z; v0.w -= m0.w;
            v1.x -= m1.x; v1.y -= m1.y; v1.z -= m1.z; v1.w -= m1.w;
        }
#pragma unroll
        for (int c = 0; c < NCOLS; ++c) { t0[c][i] = v0; t1[c][i] = v1; }
    }
    float4 ms0 = {0, 0, 0, 0}, ms1 = {0, 0, 0, 0};
    if (mu_s) { ms0 = ((const float4*)mu_s)[2 * q]; ms1 = ((const float4*)mu_s)[2 * q + 1]; }
    __syncthreads();   // pl ready; only barrier

    // bin descriptors
    int p0a[NCOLS][2], da[NCOLS][2];
#pragma unroll
    for (int c = 0; c < NCOLS; ++c)
#pragma unroll
        for (int i = 0; i < 2; ++i) {
            int r = w * 16 + i * 8 + g;
            int p0 = pl[c][r];
            p0a[c][i] = p0;
            da[c][i] = pl[c][r + 1] - p0;
        }

    // col prefetch: first two cols of every bin (clamped, independent loads)
    int cv0[NCOLS][2], cv1[NCOLS][2];
#pragma unroll
    for (int c = 0; c < NCOLS; ++c)
#pragma unroll
        for (int i = 0; i < 2; ++i) {
            int p0 = p0a[c][i];
            cv0[c][i] = col[min(p0,     TOTE - 1)];
            cv1[c][i] = col[min(p0 + 1, TOTE - 1)];
        }

    // edge slot 0: first edge of every bin (dummy row 0 when empty -> hot line)
    {
        float4 u0[NCOLS][2], u1[NCOLS][2];
#pragma unroll
        for (int c = 0; c < NCOLS; ++c)
#pragma unroll
            for (int i = 0; i < 2; ++i) {
                int v = (da[c][i] > 0) ? cv0[c][i] : 0;
                const float4* sp = (const float4*)(h_src + (size_t)v * D);
                u0[c][i] = sp[2 * q];
                u1[c][i] = sp[2 * q + 1];
            }
#pragma unroll
        for (int c = 0; c < NCOLS; ++c)
#pragma unroll
            for (int i = 0; i < 2; ++i) {
                float m = (da[c][i] > 0) ? 1.0f : 0.0f;
                t0[c][i].x = fmaf(m, u0[c][i].x, t0[c][i].x);
                t0[c][i].y = fmaf(m, u0[c][i].y, t0[c][i].y);
                t0[c][i].z = fmaf(m, u0[c][i].z, t0[c][i].z);
                t0[c][i].w = fmaf(m, u0[c][i].w, t0[c][i].w);
                t1[c][i].x = fmaf(m, u1[c][i].x, t1[c][i].x);
                t1[c][i].y = fmaf(m, u1[c][i].y, t1[c][i].y);
                t1[c][i].z = fmaf(m, u1[c][i].z, t1[c][i].z);
                t1[c][i].w = fmaf(m, u1[c][i].w, t1[c][i].w);
            }
    }
    // edge slot 1: second edge of every bin
    {
        float4 u0[NCOLS][2], u1[NCOLS][2];
#pragma unroll
        for (int c = 0; c < NCOLS; ++c)
#pragma unroll
            for (int i = 0; i < 2; ++i) {
                int v = (da[c][i] > 1) ? cv1[c][i] : 0;
                const float4* sp = (const float4*)(h_src + (size_t)v * D);
                u0[c][i] = sp[2 * q];
                u1[c][i] = sp[2 * q + 1];
            }
#pragma unroll
        for (int c = 0; c < NCOLS; ++c)
#pragma unroll
            for (int i = 0; i < 2; ++i) {
                float m = (da[c][i] > 1) ? 1.0f : 0.0f;
                t0[c][i].x = fmaf(m, u0[c][i].x, t0[c][i].x);
                t0[c][i].y = fmaf(m, u0[c][i].y, t0[c][i].y);
                t0[c][i].z = fmaf(m, u0[c][i].z, t0[c][i].z);
                t0[c][i].w = fmaf(m, u0[c][i].w, t0[c][i].w);
                t1[c][i].x = fmaf(m, u1[c][i].x, t1[c][i].x);
                t1[c][i].y = fmaf(m, u1[c][i].y, t1[c][i].y);
                t1[c][i].z = fmaf(m, u1[c][i].z, t1[c][i].z);
                t1[c][i].w = fmaf(m, u1[c][i].w, t1[c][i].w);
            }
    }
    // rare fallback: bins with deg > 2 (cell ~0.2%, rid ~8%)
#pragma unroll
    for (int c = 0; c < NCOLS; ++c)
#pragma unroll
        for (int i = 0; i < 2; ++i) {
            if (da[c][i] > 2) {
                int p0 = p0a[c][i], p1 = p0 + da[c][i];
                for (int e = p0 + 2; e < p1; ++e) {
                    int v = col[e];
                    const float4* sp = (const float4*)(h_src + (size_t)v * D);
                    float4 a = sp[2 * q], b = sp[2 * q + 1];
                    t0[c][i].x += a.x; t0[c][i].y += a.y;
                    t0[c][i].z += a.z; t0[c][i].w += a.w;
                    t1[c][i].x += b.x; t1[c][i].y += b.y;
                    t1[c][i].z += b.z; t1[c][i].w += b.w;
                }
            }
        }

    // per relation: scale -> packed bf16 hi/lo -> LDS -> MFMA accumulate
    f32x4 macc[4] = {};
#pragma unroll
    for (int c = 0; c < NCOLS; ++c) {
#pragma unroll
        for (int i = 0; i < 2; ++i) {
            int rloc = i * 8 + g;
            float dg = (float)da[c][i];
            float scv = 1.0f / (dg + 1.0f);
            float4 a = t0[c][i], b = t1[c][i];
            a.x = (a.x - dg * ms0.x) * scv; a.y = (a.y - dg * ms0.y) * scv;
            a.z = (a.z - dg * ms0.z) * scv; a.w = (a.w - dg * ms0.w) * scv;
            b.x = (b.x - dg * ms1.x) * scv; b.y = (b.y - dg * ms1.y) * scv;
            b.z = (b.z - dg * ms1.z) * scv; b.w = (b.w - dg * ms1.w) * scv;
            unsigned int h01 = cvtpk(a.x, a.y), h23 = cvtpk(a.z, a.w);
            unsigned int h45 = cvtpk(b.x, b.y), h67 = cvtpk(b.z, b.w);
            float r0 = a.x - __uint_as_float(h01 << 16);
            float r1 = a.y - __uint_as_float(h01 & 0xFFFF0000u);
            float r2 = a.z - __uint_as_float(h23 << 16);
            float r3 = a.w - __uint_as_float(h23 & 0xFFFF0000u);
            float r4 = b.x - __uint_as_float(h45 << 16);
            float r5 = b.y - __uint_as_float(h45 & 0xFFFF0000u);
            float r6 = b.z - __uint_as_float(h67 << 16);
            float r7 = b.w - __uint_as_float(h67 & 0xFFFF0000u);
            unsigned int l01 = cvtpk(r0, r1), l23 = cvtpk(r2, r3);
            unsigned int l45 = cvtpk(r4, r5), l67 = cvtpk(r6, r7);
            int off = swz(rloc, q * 16);
            *(unsigned long long*)((char*)aHi[w] + off) =
                (unsigned long long)h01 | ((unsigned long long)h23 << 32);
            *(unsigned long long*)((char*)aHi[w] + off + 8) =
                (unsigned long long)h45 | ((unsigned long long)h67 << 32);
            *(unsigned long long*)((char*)aLo[w] + off) =
                (unsigned long long)l01 | ((unsigned long long)l23 << 32);
            *(unsigned long long*)((char*)aLo[w] + off + 8) =
                (unsigned long long)l45 | ((unsigned long long)l67 << 32);
        }
        // wave-local LDS RAW (compiler inserts lgkmcnt)
        bf16x8 ah[2], al[2];
#pragma unroll
        for (int kh = 0; kh < 2; ++kh) {
            int off = swz(l & 15, kh * 64 + (l >> 4) * 16);
            ah[kh] = *(const bf16x8*)((const char*)aHi[w] + off);
            al[kh] = *(const bf16x8*)((const char*)aLo[w] + off);
        }
        // JIT W fragments (L1/L2-resident 32 KB set) + MFMA accumulate
#pragma unroll
        for (int nt = 0; nt < 4; ++nt) {
            const unsigned short* wb = Wt + ((c * D + nt * 16 + (l & 15)) * D + (l >> 4) * 8);
            bf16x8 w0 = *(const bf16x8*)(wb);
            bf16x8 w1 = *(const bf16x8*)(wb + 32);
            macc[nt] = __builtin_amdgcn_mfma_f32_16x16x32_bf16(ah[0], w0, macc[nt], 0, 0, 0);
            macc[nt] = __builtin_amdgcn_mfma_f32_16x16x32_bf16(ah[1], w1, macc[nt], 0, 0, 0);
            macc[nt] = __builtin_amdgcn_mfma_f32_16x16x32_bf16(al[0], w0, macc[nt], 0, 0, 0);
            macc[nt] = __builtin_amdgcn_mfma_f32_16x16x32_bf16(al[1], w1, macc[nt], 0, 0, 0);
        }
    }

    // epilogue: wave-local store + fused column-sum
    const int j0 = l & 15;
    float bbv[4];
#pragma unroll
    for (int nt = 0; nt < 4; ++nt)
        bbv[nt] = 0.25f * (bias[nt * 16 + j0] + bias[64 + nt * 16 + j0] +
                           bias[128 + nt * 16 + j0] + bias[192 + nt * 16 + j0]);
    float cs[4] = {0.f, 0.f, 0.f, 0.f};
#pragma unroll
    for (int nt = 0; nt < 4; ++nt)
#pragma unroll
        for (int qq = 0; qq < 4; ++qq) {
            int grow = row0 + w * 16 + (l >> 4) * 4 + qq;
            if (grow < n_dst) {
                float v = 0.25f * macc[nt][qq] + bbv[nt];
                out[(size_t)grow * D + nt * 16 + j0] = v;
                cs[nt] += v;
            }
        }
#pragma unroll
    for (int nt = 0; nt < 4; ++nt) {
        float v = cs[nt];
        v += __shfl_xor(v, 16);
        v += __shfl_xor(v, 32);
        if (l < 16) atomicAdd(&csum[(blockIdx.x & 15) * 64 + nt * 16 + l], v);
    }
}

// ----------------- reduce 16 replicas -> mean vector
__global__ void finalize16(const float* __restrict__ rep, float* __restrict__ mu,
                           float inv_n) {
    int j = threadIdx.x;   // 64 threads
    float s = 0.f;
    for (int k = 0; k < 16; ++k) s += rep[k * 64 + j];
    mu[j] = s * inv_n;
}

// ----------------- combine + center + relu (in place on out)
__global__ void final_combine(float* __restrict__ out, const float* __restrict__ rid,
        const float* __restrict__ mu_c, const float* __restrict__ mu_r) {
    int t = blockIdx.x * 256 + threadIdx.x;
    if (t >= N_CELL * D) return;
    int row = t >> 6, j = t & 63;
    float v = (row < N_RID) ? (rid[(size_t)row * D + j] - mu_r[j])
                            : (out[t] - mu_c[j]);
    out[t] = fmaxf(v, 0.0f);
}

extern "C" void kernel_launch(void* const* d_in, const int* in_sizes, int n_in,
                              void* d_out, int out_size, void* d_ws, size_t ws_size,
                              hipStream_t stream) {
    const float* x_rid  = (const float*)d_in[0];
    const float* x_cell = (const float*)d_in[1];
    const int* src_fwd  = (const int*)d_in[2];
    const int* dst_fwd  = (const int*)d_in[3];
    const int* src_rev  = (const int*)d_in[4];
    const int* dst_rev  = (const int*)d_in[5];
    const float* W1f = (const float*)d_in[6];
    const float* b1f = (const float*)d_in[7];
    const float* W1r = (const float*)d_in[8];
    const float* b1r = (const float*)d_in[9];
    const float* W2f = (const float*)d_in[10];
    const float* b2f = (const float*)d_in[11];
    const float* W2r = (const float*)d_in[12];
    const float* b2r = (const float*)d_in[13];
    float* out = (float*)d_out;

    float* ws    = (float*)d_ws;
    float* rid1  = ws;                                   //  6.4M f32
    float* cell1 = rid1  + (size_t)N_RID * D;            // 25.6M
    float* rid2  = cell1 + (size_t)N_CELL * D;           //  6.4M (build overlays)
    float* csums = rid2  + (size_t)N_RID * D;            //  4 x 1024
    float* mus   = csums + 4 * 1024;                     //  4 x 64
    int*   ptrF  = (int*)(mus + 4 * 64);
    int*   colF  = ptrF + (size_t)NCOLS * N_CELL + 1;
    int*   ptrR  = colF + TOTE;
    int*   colR  = ptrR + (size_t)NCOLS * N_RID + 1;
    uintptr_t wp = ((uintptr_t)(colR + TOTE) + 15) & ~(uintptr_t)15;
    unsigned short* Wt1f = (unsigned short*)wp;
    unsigned short* Wt1r = Wt1f + NCOLS * D * D;
    unsigned short* Wt2f = Wt1r + NCOLS * D * D;
    unsigned short* Wt2r = Wt2f + NCOLS * D * D;
    // build-phase overlays inside rid2 region (dead until layer 2)
    int*   cntF  = (int*)rid2;
    int*   cntR  = cntF + (size_t)NCOLS * N_CELL;
    int*   csumF = cntR + (size_t)NCOLS * N_RID;
    int*   csumR = csumF + 2048;

    float* cs_c1 = csums;
    float* cs_r1 = csums + 1024;
    float* cs_o  = csums + 2048;
    float* cs_r2 = csums + 3072;
    float* mu_c1 = mus;
    float* mu_r1 = mus + 64;
    float* mu_o  = mus + 128;
    float* mu_r2 = mus + 192;

    const int NBF = NCOLS * N_CELL;
    const int NBR = NCOLS * N_RID;
    const int g_edges = (TOTE + 255) / 256;

    hipMemsetAsync(cntF, 0, (size_t)NBF * sizeof(int), stream);
    hipMemsetAsync(cntR, 0, (size_t)NBR * sizeof(int), stream);
    hipMemsetAsync(csums, 0, 4 * 1024 * sizeof(float), stream);

    prep_w<<<(NCOLS * D * D + 255) / 256, 256, 0, stream>>>(W1f, W1r, W2f, W2r,
                                                            Wt1f, Wt1r, Wt2f, Wt2r);

    hist_kernel<<<g_edges, 256, 0, stream>>>(dst_fwd, cntF, N_CELL);
    hist_kernel<<<g_edges, 256, 0, stream>>>(dst_rev, cntR, N_RID);
    int nchF = (NBF + 1023) / 1024, nchR = (NBR + 1023) / 1024;
    scan1<<<nchF, 256, 0, stream>>>(cntF, ptrF, csumF, NBF);
    scan2<<<1, 256, 0, stream>>>(csumF, nchF);
    scan3<<<(NBF + 255) / 256, 256, 0, stream>>>(ptrF, csumF, NBF);
    scan1<<<nchR, 256, 0, stream>>>(cntR, ptrR, csumR, NBR);
    scan2<<<1, 256, 0, stream>>>(csumR, nchR);
    scan3<<<(NBR + 255) / 256, 256, 0, stream>>>(ptrR, csumR, NBR);
    set_sentinels<<<1, 64, 0, stream>>>(ptrF, ptrR);
    fill_kernel<<<g_edges, 256, 0, stream>>>(dst_fwd, src_fwd, ptrF, cntF, colF, N_CELL);
    fill_kernel<<<g_edges, 256, 0, stream>>>(dst_rev, src_rev, ptrR, cntR, colR, N_RID);

    const int gC = N_CELL / TILE;                 // 6250
    const int gR = (N_RID + TILE - 1) / TILE;     // 1563

    // ---------------- layer 1 ----------------
    sage_fused<<<gC, 256, 0, stream>>>(x_cell, x_rid, ptrF, colF, Wt1f, b1f,
                                       nullptr, nullptr, cell1, cs_c1, N_CELL);
    sage_fused<<<gR, 256, 0, stream>>>(x_rid, x_cell, ptrR, colR, Wt1r, b1r,
                                       nullptr, nullptr, rid1, cs_r1, N_RID);
    finalize16<<<1, 64, 0, stream>>>(cs_c1, mu_c1, 1.0f / N_CELL);
    finalize16<<<1, 64, 0, stream>>>(cs_r1, mu_r1, 1.0f / N_RID);

    // ---------------- layer 2 ----------------
    sage_fused<<<gC, 256, 0, stream>>>(cell1, rid1, ptrF, colF, Wt2f, b2f,
                                       mu_c1, mu_r1, out, cs_o, N_CELL);
    sage_fused<<<gR, 256, 0, stream>>>(rid1, cell1, ptrR, colR, Wt2r, b2r,
                                       mu_r1, mu_c1, rid2, cs_r2, N_RID);
    finalize16<<<1, 64, 0, stream>>>(cs_o, mu_o, 1.0f / N_CELL);
    finalize16<<<1, 64, 0, stream>>>(cs_r2, mu_r2, 1.0f / N_RID);

    final_combine<<<(N_CELL * D) / 256, 256, 0, stream>>>(out, rid2, mu_o, mu_r2);
}

// Round 10
// 606.278 us; speedup vs baseline: 1.0741x; 1.0741x over previous
//
#include <hip/hip_runtime.h>

#define N_RID  100000
#define N_CELL 400000
#define NCOLS  4
#define NE     100000
#define D      64
#define TOTE   (NCOLS * NE)          // 400000 edges per direction
#define TILE   64                    // rows per block
#define NBF    (NCOLS * N_CELL)
#define NBR    (NCOLS * N_RID)
#define NCHF   ((NBF + 1023) / 1024) // 1563
#define NCHR   ((NBR + 1023) / 1024) // 391

typedef __attribute__((ext_vector_type(8))) short bf16x8;
typedef __attribute__((ext_vector_type(4))) float f32x4;

__device__ inline unsigned short f2bf(float f) {
    unsigned int u = __float_as_uint(f);
    return (unsigned short)((u + 0x7FFF + ((u >> 16) & 1)) >> 16);
}
__device__ inline float bf2f(unsigned short b) {
    return __uint_as_float(((unsigned int)b) << 16);
}
// packed 2xf32 -> 2xbf16 (low16 = a, high16 = b)
__device__ inline unsigned int cvtpk(float a, float b) {
    unsigned int r;
    asm("v_cvt_pk_bf16_f32 %0, %1, %2" : "=v"(r) : "v"(a), "v"(b));
    return r;
}
// byte offset within a [16 rows][128B] bf16 tile, XOR-swizzled
__device__ inline int swz(int row, int kbyte) {
    return row * 128 + (kbyte ^ ((row & 7) << 4));
}
// load one feature row's 8 columns [q*8, q*8+8) as two float4
template<bool BF>
__device__ inline void ldrow(const void* h, size_t row, int q, float4& a, float4& b) {
    if (BF) {
        const unsigned short* p = (const unsigned short*)h + row * D + q * 8;
        bf16x8 r = *(const bf16x8*)p;
        a.x = bf2f((unsigned short)r[0]); a.y = bf2f((unsigned short)r[1]);
        a.z = bf2f((unsigned short)r[2]); a.w = bf2f((unsigned short)r[3]);
        b.x = bf2f((unsigned short)r[4]); b.y = bf2f((unsigned short)r[5]);
        b.z = bf2f((unsigned short)r[6]); b.w = bf2f((unsigned short)r[7]);
    } else {
        const float4* p = (const float4*)((const float*)h + row * D);
        a = p[2 * q]; b = p[2 * q + 1];
    }
}

// ================================================================ CSR build (merged F+R)
__global__ void hist2(const int* __restrict__ dstF, const int* __restrict__ dstR,
                      int* __restrict__ cntF, int* __restrict__ cntR) {
    int t = blockIdx.x * 256 + threadIdx.x;
    if (t < TOTE) {
        int c = t / NE;
        atomicAdd(&cntF[c * N_CELL + dstF[t]], 1);
    } else if (t < 2 * TOTE) {
        int t2 = t - TOTE;
        int c = t2 / NE;
        atomicAdd(&cntR[c * N_RID + dstR[t2]], 1);
    }
}

__global__ void scan1_2(const int* __restrict__ inF, int* __restrict__ outF,
                        int* __restrict__ csF, const int* __restrict__ inR,
                        int* __restrict__ outR, int* __restrict__ csR) {
    __shared__ int lds[256];
    const int b = blockIdx.x;
    const int* in; int* outp; int* cs; int n, bb;
    if (b < NCHF) { in = inF; outp = outF; cs = csF; n = NBF; bb = b; }
    else          { in = inR; outp = outR; cs = csR; n = NBR; bb = b - NCHF; }
    int base = bb * 1024 + threadIdx.x * 4;
    int v0 = 0, v1 = 0, v2 = 0, v3 = 0;
    if (base + 0 < n) v0 = in[base + 0];
    if (base + 1 < n) v1 = in[base + 1];
    if (base + 2 < n) v2 = in[base + 2];
    if (base + 3 < n) v3 = in[base + 3];
    int tsum = v0 + v1 + v2 + v3;
    lds[threadIdx.x] = tsum;
    __syncthreads();
    for (int off = 1; off < 256; off <<= 1) {
        int x = (threadIdx.x >= off) ? lds[threadIdx.x - off] : 0;
        __syncthreads();
        lds[threadIdx.x] += x;
        __syncthreads();
    }
    int excl = lds[threadIdx.x] - tsum;
    if (base + 0 < n) outp[base + 0] = excl;
    if (base + 1 < n) outp[base + 1] = excl + v0;
    if (base + 2 < n) outp[base + 2] = excl + v0 + v1;
    if (base + 3 < n) outp[base + 3] = excl + v0 + v1 + v2;
    if (threadIdx.x == 255) cs[bb] = lds[255];
}

__global__ void scan2_2(int* __restrict__ aF, int* __restrict__ aR) {
    __shared__ int lds[256];
    int* a = blockIdx.x ? aR : aF;
    int m  = blockIdx.x ? NCHR : NCHF;
    int per = (m + 255) >> 8;
    int st = threadIdx.x * per;
    int s = 0;
    for (int i = 0; i < per; ++i) if (st + i < m) s += a[st + i];
    lds[threadIdx.x] = s;
    __syncthreads();
    for (int off = 1; off < 256; off <<= 1) {
        int x = (threadIdx.x >= off) ? lds[threadIdx.x - off] : 0;
        __syncthreads();
        lds[threadIdx.x] += x;
        __syncthreads();
    }
    int run = lds[threadIdx.x] - s;
    for (int i = 0; i < per; ++i) if (st + i < m) { int v = a[st + i]; a[st + i] = run; run += v; }
}

__global__ void scan3_2(int* __restrict__ outF, const int* __restrict__ csF,
                        int* __restrict__ outR, const int* __restrict__ csR) {
    const int gF = (NBF + 255) / 256;
    int b = blockIdx.x;
    if (b == 0 && threadIdx.x == 0) { outF[NBF] = TOTE; outR[NBR] = TOTE; }
    if (b < gF) {
        int i = b * 256 + threadIdx.x;
        if (i < NBF) outF[i] += csF[i >> 10];
    } else {
        int i = (b - gF) * 256 + threadIdx.x;
        if (i < NBR) outR[i] += csR[i >> 10];
    }
}

__global__ void fill2(const int* __restrict__ dstF, const int* __restrict__ srcF,
                      const int* __restrict__ ptrF, int* __restrict__ cntF,
                      int* __restrict__ colF,
                      const int* __restrict__ dstR, const int* __restrict__ srcR,
                      const int* __restrict__ ptrR, int* __restrict__ cntR,
                      int* __restrict__ colR) {
    int t = blockIdx.x * 256 + threadIdx.x;
    if (t < TOTE) {
        int c = t / NE;
        int bin = c * N_CELL + dstF[t];
        int old = atomicSub(&cntF[bin], 1);
        colF[ptrF[bin] + old - 1] = srcF[t];
    } else if (t < 2 * TOTE) {
        int t2 = t - TOTE;
        int c = t2 / NE;
        int bin = c * N_RID + dstR[t2];
        int old = atomicSub(&cntR[bin], 1);
        colR[ptrR[bin] + old - 1] = srcR[t2];
    }
}

// ---------------- W prep: Wt[c][j][k] = bf16(W[c][k][j]) for 4 weight sets
__global__ void prep_w(const float* __restrict__ Wa, const float* __restrict__ Wb,
                       const float* __restrict__ Wc, const float* __restrict__ Wd,
                       unsigned short* __restrict__ Ta, unsigned short* __restrict__ Tb,
                       unsigned short* __restrict__ Tc, unsigned short* __restrict__ Td) {
    int t = blockIdx.x * 256 + threadIdx.x;
    if (t >= NCOLS * D * D) return;
    int c = t >> 12, jk = t & 4095, j = jk >> 6, k = jk & 63;
    int s = (c * D + k) * D + j;
    Ta[t] = f2bf(Wa[s]);
    Tb[t] = f2bf(Wb[s]);
    Tc[t] = f2bf(Wc[s]);
    Td[t] = f2bf(Wd[s]);
}

// ============================ unified SAGE layer kernel ======================
// ONE dispatch per layer covers BOTH destination node types: blocks < gC do
// the cell side, the rest do the rid side (uniform branch). Wave w owns rows
// [w*16,w*16+16) for all 4 relations (sequential), pre-scaled into one MFMA
// accumulator. INBF/OUTBF select f32 vs bf16 feature storage.
template<bool INBF, bool OUTBF>
__global__ void __launch_bounds__(256, 5) sage2(
        const void* __restrict__ hdC, const void* __restrict__ hsC,
        const int* __restrict__ ptrC, const int* __restrict__ colC,
        const unsigned short* __restrict__ WtC, const float* __restrict__ biasC,
        const float* __restrict__ mudC, const float* __restrict__ musC,
        void* __restrict__ outC, float* __restrict__ csC,
        const void* __restrict__ hdR, const void* __restrict__ hsR,
        const int* __restrict__ ptrR, const int* __restrict__ colR,
        const unsigned short* __restrict__ WtR, const float* __restrict__ biasR,
        const float* __restrict__ mudR, const float* __restrict__ musR,
        void* __restrict__ outR, float* __restrict__ csR, int gC) {
    __shared__ int pl[NCOLS][TILE + 1];              // ~1 KB
    __shared__ unsigned short aHi[4][16 * D];        // 8 KB
    __shared__ unsigned short aLo[4][16 * D];        // 8 KB

    const int tid = threadIdx.x, w = tid >> 6, l = tid & 63;
    const int g = l >> 3, q = l & 7;

    const bool rrole = (int)blockIdx.x >= gC;
    const void* h_dst = rrole ? hdR : hdC;
    const void* h_src = rrole ? hsR : hsC;
    const int* ptr    = rrole ? ptrR : ptrC;
    const int* col    = rrole ? colR : colC;
    const unsigned short* Wt = rrole ? WtR : WtC;
    const float* bias = rrole ? biasR : biasC;
    const float* mu_d = rrole ? mudR : mudC;
    const float* mu_s = rrole ? musR : musC;
    void* out   = rrole ? outR : outC;
    float* csum = rrole ? csR : csC;
    const int n_dst = rrole ? N_RID : N_CELL;
    const int row0 = (rrole ? (int)blockIdx.x - gC : (int)blockIdx.x) * TILE;

    // coalesced ptr prefetch (clamped; sentinel entry valid; relation
    // boundaries coincide with bin boundaries so clamping is consistent)
    for (int i = tid; i < NCOLS * (TILE + 1); i += 256) {
        int cc = i / (TILE + 1), r = i % (TILE + 1);
        pl[cc][r] = ptr[(size_t)cc * n_dst + min(row0 + r, n_dst)];
    }

    // self term (h_dst - mu_d) for the wave's 2 owned rows, fanned to 4 relations
    float4 t0[NCOLS][2], t1[NCOLS][2];
#pragma unroll
    for (int i = 0; i < 2; ++i) {
        int re = min(row0 + w * 16 + i * 8 + g, n_dst - 1);
        float4 v0, v1;
        ldrow<INBF>(h_dst, (size_t)re, q, v0, v1);
        if (mu_d) {
            float4 m0 = ((const float4*)mu_d)[2 * q], m1 = ((const float4*)mu_d)[2 * q + 1];
            v0.x -= m0.x; v0.y -= m0.y; v0.z -= m0.z; v0.w -= m0.w;
            v1.x -= m1.x; v1.y -= m1.y; v1.z -= m1.z; v1.w -= m1.w;
        }
#pragma unroll
        for (int c = 0; c < NCOLS; ++c) { t0[c][i] = v0; t1[c][i] = v1; }
    }
    float4 ms0 = {0, 0, 0, 0}, ms1 = {0, 0, 0, 0};
    if (mu_s) { ms0 = ((const float4*)mu_s)[2 * q]; ms1 = ((const float4*)mu_s)[2 * q + 1]; }
    __syncthreads();   // pl ready; only barrier

    // gather: each group walks its own rows' edge lists
#pragma unroll
    for (int c = 0; c < NCOLS; ++c)
#pragma unroll
        for (int i = 0; i < 2; ++i) {
            int r = w * 16 + i * 8 + g;
            int p0 = pl[c][r], p1 = pl[c][r + 1];
            for (int e = p0; e < p1; ++e) {
                float4 u0, u1;
                ldrow<INBF>(h_src, (size_t)col[e], q, u0, u1);
                t0[c][i].x += u0.x; t0[c][i].y += u0.y;
                t0[c][i].z += u0.z; t0[c][i].w += u0.w;
                t1[c][i].x += u1.x; t1[c][i].y += u1.y;
                t1[c][i].z += u1.z; t1[c][i].w += u1.w;
            }
        }

    // per relation: scale -> packed bf16 hi/lo -> LDS -> MFMA accumulate
    f32x4 macc[4] = {};
#pragma unroll
    for (int c = 0; c < NCOLS; ++c) {
#pragma unroll
        for (int i = 0; i < 2; ++i) {
            int rloc = i * 8 + g;
            int row = w * 16 + rloc;
            float dg = (float)(pl[c][row + 1] - pl[c][row]);
            float scv = 1.0f / (dg + 1.0f);
            float4 a = t0[c][i], b = t1[c][i];
            a.x = (a.x - dg * ms0.x) * scv; a.y = (a.y - dg * ms0.y) * scv;
            a.z = (a.z - dg * ms0.z) * scv; a.w = (a.w - dg * ms0.w) * scv;
            b.x = (b.x - dg * ms1.x) * scv; b.y = (b.y - dg * ms1.y) * scv;
            b.z = (b.z - dg * ms1.z) * scv; b.w = (b.w - dg * ms1.w) * scv;
            unsigned int h01 = cvtpk(a.x, a.y), h23 = cvtpk(a.z, a.w);
            unsigned int h45 = cvtpk(b.x, b.y), h67 = cvtpk(b.z, b.w);
            float r0 = a.x - __uint_as_float(h01 << 16);
            float r1 = a.y - __uint_as_float(h01 & 0xFFFF0000u);
            float r2 = a.z - __uint_as_float(h23 << 16);
            float r3 = a.w - __uint_as_float(h23 & 0xFFFF0000u);
            float r4 = b.x - __uint_as_float(h45 << 16);
            float r5 = b.y - __uint_as_float(h45 & 0xFFFF0000u);
            float r6 = b.z - __uint_as_float(h67 << 16);
            float r7 = b.w - __uint_as_float(h67 & 0xFFFF0000u);
            unsigned int l01 = cvtpk(r0, r1), l23 = cvtpk(r2, r3);
            unsigned int l45 = cvtpk(r4, r5), l67 = cvtpk(r6, r7);
            int off = swz(rloc, q * 16);
            *(unsigned long long*)((char*)aHi[w] + off) =
                (unsigned long long)h01 | ((unsigned long long)h23 << 32);
            *(unsigned long long*)((char*)aHi[w] + off + 8) =
                (unsigned long long)h45 | ((unsigned long long)h67 << 32);
            *(unsigned long long*)((char*)aLo[w] + off) =
                (unsigned long long)l01 | ((unsigned long long)l23 << 32);
            *(unsigned long long*)((char*)aLo[w] + off + 8) =
                (unsigned long long)l45 | ((unsigned long long)l67 << 32);
        }
        // wave-local LDS RAW (compiler inserts lgkmcnt)
        bf16x8 ah[2], al[2];
#pragma unroll
        for (int kh = 0; kh < 2; ++kh) {
            int off = swz(l & 15, kh * 64 + (l >> 4) * 16);
            ah[kh] = *(const bf16x8*)((const char*)aHi[w] + off);
            al[kh] = *(const bf16x8*)((const char*)aLo[w] + off);
        }
        // JIT W fragments (L1/L2-resident 32 KB set) + MFMA accumulate
#pragma unroll
        for (int nt = 0; nt < 4; ++nt) {
            const unsigned short* wb = Wt + ((c * D + nt * 16 + (l & 15)) * D + (l >> 4) * 8);
            bf16x8 w0 = *(const bf16x8*)(wb);
            bf16x8 w1 = *(const bf16x8*)(wb + 32);
            macc[nt] = __builtin_amdgcn_mfma_f32_16x16x32_bf16(ah[0], w0, macc[nt], 0, 0, 0);
            macc[nt] = __builtin_amdgcn_mfma_f32_16x16x32_bf16(ah[1], w1, macc[nt], 0, 0, 0);
            macc[nt] = __builtin_amdgcn_mfma_f32_16x16x32_bf16(al[0], w0, macc[nt], 0, 0, 0);
            macc[nt] = __builtin_amdgcn_mfma_f32_16x16x32_bf16(al[1], w1, macc[nt], 0, 0, 0);
        }
    }

    // epilogue: wave-local store + fused column-sum
    const int j0 = l & 15;
    float bbv[4];
#pragma unroll
    for (int nt = 0; nt < 4; ++nt)
        bbv[nt] = 0.25f * (bias[nt * 16 + j0] + bias[64 + nt * 16 + j0] +
                           bias[128 + nt * 16 + j0] + bias[192 + nt * 16 + j0]);
    float cs[4] = {0.f, 0.f, 0.f, 0.f};
#pragma unroll
    for (int nt = 0; nt < 4; ++nt)
#pragma unroll
        for (int qq = 0; qq < 4; ++qq) {
            int grow = row0 + w * 16 + (l >> 4) * 4 + qq;
            if (grow < n_dst) {
                float v = 0.25f * macc[nt][qq] + bbv[nt];
                if (OUTBF)
                    ((unsigned short*)out)[(size_t)grow * D + nt * 16 + j0] = f2bf(v);
                else
                    ((float*)out)[(size_t)grow * D + nt * 16 + j0] = v;
                cs[nt] += v;
            }
        }
#pragma unroll
    for (int nt = 0; nt < 4; ++nt) {
        float v = cs[nt];
        v += __shfl_xor(v, 16);
        v += __shfl_xor(v, 32);
        if (l < 16) atomicAdd(&csum[(blockIdx.x & 15) * 64 + nt * 16 + l], v);
    }
}

// ----------------- reduce 16 replicas -> mean vectors (both node types)
__global__ void finalize2(const float* __restrict__ repA, float* __restrict__ muA,
                          float invA, const float* __restrict__ repB,
                          float* __restrict__ muB, float invB) {
    int j = threadIdx.x;   // 64 threads
    const float* rep = blockIdx.x ? repB : repA;
    float* mu        = blockIdx.x ? muB : muA;
    float inv        = blockIdx.x ? invB : invA;
    float s = 0.f;
    for (int k = 0; k < 16; ++k) s += rep[k * 64 + j];
    mu[j] = s * inv;
}

// ----------------- combine + center + relu (in place on out)
__global__ void final_combine(float* __restrict__ out, const float* __restrict__ rid,
        const float* __restrict__ mu_c, const float* __restrict__ mu_r) {
    int t = blockIdx.x * 256 + threadIdx.x;
    if (t >= N_CELL * D) return;
    int row = t >> 6, j = t & 63;
    float v = (row < N_RID) ? (rid[(size_t)row * D + j] - mu_r[j])
                            : (out[t] - mu_c[j]);
    out[t] = fmaxf(v, 0.0f);
}

extern "C" void kernel_launch(void* const* d_in, const int* in_sizes, int n_in,
                              void* d_out, int out_size, void* d_ws, size_t ws_size,
                              hipStream_t stream) {
    const float* x_rid  = (const float*)d_in[0];
    const float* x_cell = (const float*)d_in[1];
    const int* src_fwd  = (const int*)d_in[2];
    const int* dst_fwd  = (const int*)d_in[3];
    const int* src_rev  = (const int*)d_in[4];
    const int* dst_rev  = (const int*)d_in[5];
    const float* W1f = (const float*)d_in[6];
    const float* b1f = (const float*)d_in[7];
    const float* W1r = (const float*)d_in[8];
    const float* b1r = (const float*)d_in[9];
    const float* W2f = (const float*)d_in[10];
    const float* b2f = (const float*)d_in[11];
    const float* W2r = (const float*)d_in[12];
    const float* b2r = (const float*)d_in[13];
    float* out = (float*)d_out;

    char* p = (char*)d_ws;
    float* rid2 = (float*)p;                     p += (size_t)N_RID * D * 4;   // 25.6 MB (build overlays live here)
    unsigned short* cell1 = (unsigned short*)p;  p += (size_t)N_CELL * D * 2;  // 51.2 MB
    unsigned short* rid1  = (unsigned short*)p;  p += (size_t)N_RID * D * 2;   // 12.8 MB
    float* csums = (float*)p;                    p += 4 * 1024 * 4;
    float* mus   = (float*)p;                    p += 4 * 64 * 4;
    int* ptrF = (int*)p;                         p += (size_t)(NBF + 4) * 4;
    int* colF = (int*)p;                         p += (size_t)TOTE * 4;
    int* ptrR = (int*)p;                         p += (size_t)(NBR + 4) * 4;
    int* colR = (int*)p;                         p += (size_t)TOTE * 4;
    unsigned short* Wt1f = (unsigned short*)p;   p += NCOLS * D * D * 2;
    unsigned short* Wt1r = (unsigned short*)p;   p += NCOLS * D * D * 2;
    unsigned short* Wt2f = (unsigned short*)p;   p += NCOLS * D * D * 2;
    unsigned short* Wt2r = (unsigned short*)p;   p += NCOLS * D * D * 2;
    // build-phase overlays inside rid2 region (8.02 MB < 25.6 MB; dead by layer 2)
    int* cntF  = (int*)rid2;
    int* cntR  = cntF + NBF;
    int* csumF = cntR + NBR;
    int* csumR = csumF + 2048;

    float* cs_c1 = csums;
    float* cs_r1 = csums + 1024;
    float* cs_o  = csums + 2048;
    float* cs_r2 = csums + 3072;
    float* mu_c1 = mus;
    float* mu_r1 = mus + 64;
    float* mu_o  = mus + 128;
    float* mu_r2 = mus + 192;

    hipMemsetAsync(cntF, 0, (size_t)(NBF + NBR) * sizeof(int), stream);
    hipMemsetAsync(csums, 0, 4 * 1024 * sizeof(float), stream);

    prep_w<<<(NCOLS * D * D + 255) / 256, 256, 0, stream>>>(W1f, W1r, W2f, W2r,
                                                            Wt1f, Wt1r, Wt2f, Wt2r);

    const int g2e = (2 * TOTE + 255) / 256;      // 3125
    hist2<<<g2e, 256, 0, stream>>>(dst_fwd, dst_rev, cntF, cntR);
    scan1_2<<<NCHF + NCHR, 256, 0, stream>>>(cntF, ptrF, csumF, cntR, ptrR, csumR);
    scan2_2<<<2, 256, 0, stream>>>(csumF, csumR);
    scan3_2<<<(NBF + 255) / 256 + (NBR + 255) / 256, 256, 0, stream>>>(ptrF, csumF,
                                                                       ptrR, csumR);
    fill2<<<g2e, 256, 0, stream>>>(dst_fwd, src_fwd, ptrF, cntF, colF,
                                   dst_rev, src_rev, ptrR, cntR, colR);

    const int gC = N_CELL / TILE;                 // 6250
    const int gR = (N_RID + TILE - 1) / TILE;     // 1563

    // ---------------- layer 1 (f32 in, bf16 out; both node types, one grid) --
    sage2<false, true><<<gC + gR, 256, 0, stream>>>(
        x_cell, x_rid, ptrF, colF, Wt1f, b1f, nullptr, nullptr, cell1, cs_c1,
        x_rid, x_cell, ptrR, colR, Wt1r, b1r, nullptr, nullptr, rid1, cs_r1, gC);
    finalize2<<<2, 64, 0, stream>>>(cs_c1, mu_c1, 1.0f / N_CELL,
                                    cs_r1, mu_r1, 1.0f / N_RID);

    // ---------------- layer 2 (bf16 in, f32 out) ----------------------------
    sage2<true, false><<<gC + gR, 256, 0, stream>>>(
        cell1, rid1, ptrF, colF, Wt2f, b2f, mu_c1, mu_r1, out, cs_o,
        rid1, cell1, ptrR, colR, Wt2r, b2r, mu_r1, mu_c1, rid2, cs_r2, gC);
    finalize2<<<2, 64, 0, stream>>>(cs_o, mu_o, 1.0f / N_CELL,
                                    cs_r2, mu_r2, 1.0f / N_RID);

    final_combine<<<(N_CELL * D) / 256, 256, 0, stream>>>(out, rid2, mu_o, mu_r2);
}